// Round 1
// baseline (839.147 us; speedup 1.0000x reference)
//
#include <hip/hip_runtime.h>

// Problem constants: B=2, T=4096, C=1024, H=16, D=64
constexpr int Bn = 2;
constexpr int Tn = 4096;
constexpr int Cn = 1024;
constexpr int Hn = 16;
constexpr int Dn = 64;

typedef __bf16 bf16x8 __attribute__((ext_vector_type(8)));
typedef float f32x4 __attribute__((ext_vector_type(4)));
typedef unsigned short u16x8 __attribute__((ext_vector_type(8)));

__device__ __forceinline__ unsigned short f2bf(float f) {
  unsigned int u = __float_as_uint(f);
  u += 0x7FFF + ((u >> 16) & 1);   // round-to-nearest-even
  return (unsigned short)(u >> 16);
}

__device__ __forceinline__ bf16x8 ld_bf8(const unsigned short* p) {
  return __builtin_bit_cast(bf16x8, *(const u16x8*)p);
}

// ---------------- f32 -> bf16 cast (vectorized) ----------------
__global__ void cvt_kernel(const float* __restrict__ in, unsigned short* __restrict__ out, int n4) {
  int i = blockIdx.x * blockDim.x + threadIdx.x;
  if (i >= n4) return;
  float4 v = ((const float4*)in)[i];
  ushort4 o;
  o.x = f2bf(v.x); o.y = f2bf(v.y); o.z = f2bf(v.z); o.w = f2bf(v.w);
  ((ushort4*)out)[i] = o;
}

// ---------------- GEMM: C[M][N] = A[M][K] @ B[N][K]^T (bf16 in, bf16/f32 out) ----------------
// 128x128 tile, BK=64, 256 threads = 4 waves (2x2), each wave 64x64 out (4x4 fragments 16x16)
template<int OUT_BF16>
__global__ __launch_bounds__(256) void gemm_bt(const unsigned short* __restrict__ A,
                                               const unsigned short* __restrict__ Bm,
                                               void* __restrict__ Cout,
                                               int M, int N, int K) {
  __shared__ __align__(16) unsigned short As[128][64];
  __shared__ __align__(16) unsigned short Bs[128][64];
  const int tid  = threadIdx.x;
  const int wave = tid >> 6;
  const int lane = tid & 63;
  const int wr   = (wave >> 1) * 64;   // wave row offset within tile
  const int wc   = (wave & 1) * 64;    // wave col offset within tile
  const int lrow = lane & 15;
  const int lk8  = (lane >> 4) << 3;
  const int row0 = blockIdx.y * 128;
  const int col0 = blockIdx.x * 128;

  f32x4 acc[4][4];
  #pragma unroll
  for (int i = 0; i < 4; ++i)
    #pragma unroll
    for (int j = 0; j < 4; ++j)
      acc[i][j] = (f32x4){0.f, 0.f, 0.f, 0.f};

  for (int k0 = 0; k0 < K; k0 += 64) {
    const unsigned short* Ag = A  + (size_t)row0 * K + k0;
    const unsigned short* Bg = Bm + (size_t)col0 * K + k0;
    #pragma unroll
    for (int i = 0; i < 4; ++i) {
      int flat = (i * 256 + tid) * 8;
      int r = flat >> 6, c = flat & 63;
      __builtin_amdgcn_global_load_lds((const __attribute__((address_space(1))) void*)(Ag + (size_t)r * K + c),
                                       (__attribute__((address_space(3))) void*)(&As[r][c]), 16, 0, 0);
    }
    #pragma unroll
    for (int i = 0; i < 4; ++i) {
      int flat = (i * 256 + tid) * 8;
      int r = flat >> 6, c = flat & 63;
      __builtin_amdgcn_global_load_lds((const __attribute__((address_space(1))) void*)(Bg + (size_t)r * K + c),
                                       (__attribute__((address_space(3))) void*)(&Bs[r][c]), 16, 0, 0);
    }
    __syncthreads();   // compiler drains vmcnt before s_barrier

    #pragma unroll
    for (int ks = 0; ks < 2; ++ks) {
      bf16x8 af[4], bfr[4];
      #pragma unroll
      for (int i = 0; i < 4; ++i) af[i]  = ld_bf8(&As[wr + i * 16 + lrow][ks * 32 + lk8]);
      #pragma unroll
      for (int j = 0; j < 4; ++j) bfr[j] = ld_bf8(&Bs[wc + j * 16 + lrow][ks * 32 + lk8]);
      #pragma unroll
      for (int i = 0; i < 4; ++i)
        #pragma unroll
        for (int j = 0; j < 4; ++j)
          acc[i][j] = __builtin_amdgcn_mfma_f32_16x16x32_bf16(af[i], bfr[j], acc[i][j], 0, 0, 0);
    }
    __syncthreads();
  }

  // C/D layout: col = lane&15, row = (lane>>4)*4 + reg
  const int rg = (lane >> 4) * 4;
  const int cl = lane & 15;
  #pragma unroll
  for (int i = 0; i < 4; ++i)
    #pragma unroll
    for (int j = 0; j < 4; ++j)
      #pragma unroll
      for (int rr = 0; rr < 4; ++rr) {
        int gm = row0 + wr + i * 16 + rg + rr;
        int gn = col0 + wc + j * 16 + cl;
        float v = acc[i][j][rr];
        if (OUT_BF16) ((unsigned short*)Cout)[(size_t)gm * N + gn] = f2bf(v);
        else          ((float*)Cout)[(size_t)gm * N + gn] = v;
      }
}

// ---------------- Causal flash attention ----------------
// grid = (T/64, B*H), block = 256 (4 waves x 16 q-rows). KVBLK=64, D=64.
// qkv layout: [b][t][3*C] with f = s*C + h*D + d
__global__ __launch_bounds__(256) void attn_kernel(const unsigned short* __restrict__ qkv,
                                                   unsigned short* __restrict__ outb) {
  __shared__ __align__(16) unsigned short Ks[64][64];   // [kv][d]
  __shared__ __align__(16) unsigned short Vs[64][64];   // [d][kv]  (transposed)
  __shared__ __align__(16) unsigned short Ps[4][16][64];

  const int tid  = threadIdx.x;
  const int wave = tid >> 6;
  const int lane = tid & 63;
  const int lrow = lane & 15;
  const int lk8  = (lane >> 4) << 3;
  const int rg   = (lane >> 4) * 4;

  const int qt = blockIdx.x * 64;
  const int bh = blockIdx.y;
  const int b  = bh >> 4;
  const int h  = bh & 15;

  const unsigned short* qb = qkv + (size_t)b * Tn * (3 * Cn) + h * Dn;
  const unsigned short* kb = qb + Cn;
  const unsigned short* vb = qb + 2 * Cn;

  // Q fragments for this wave's 16 rows (A-layout: row=lane&15, k=(lane>>4)*8+j)
  bf16x8 qf[2];
  {
    const unsigned short* qr = qb + (size_t)(qt + wave * 16 + lrow) * (3 * Cn) + lk8;
    qf[0] = ld_bf8(qr);
    qf[1] = ld_bf8(qr + 32);
  }

  f32x4 oacc[4];
  #pragma unroll
  for (int n = 0; n < 4; ++n) oacc[n] = (f32x4){0.f, 0.f, 0.f, 0.f};
  float mrun[4] = {-1e30f, -1e30f, -1e30f, -1e30f};
  float lrun[4] = {0.f, 0.f, 0.f, 0.f};

  const int nkv = qt / 64 + 1;
  for (int kt = 0; kt < nkv; ++kt) {
    const int kv0 = kt * 64;
    __syncthreads();   // previous tile's LDS reads done
    #pragma unroll
    for (int i = 0; i < 2; ++i) {
      int flat = (i * 256 + tid) * 8;
      int r = flat >> 6, c = flat & 63;
      *(u16x8*)&Ks[r][c] = *(const u16x8*)(kb + (size_t)(kv0 + r) * (3 * Cn) + c);
      u16x8 vv = *(const u16x8*)(vb + (size_t)(kv0 + r) * (3 * Cn) + c);
      #pragma unroll
      for (int j = 0; j < 8; ++j) Vs[c + j][r] = vv[j];
    }
    __syncthreads();

    // S = Q @ K^T   (S: 16 q-rows x 64 kv-cols per wave)
    f32x4 s[4];
    #pragma unroll
    for (int n = 0; n < 4; ++n) s[n] = (f32x4){0.f, 0.f, 0.f, 0.f};
    #pragma unroll
    for (int n = 0; n < 4; ++n)
      #pragma unroll
      for (int ks = 0; ks < 2; ++ks) {
        bf16x8 kf = ld_bf8(&Ks[n * 16 + lrow][ks * 32 + lk8]);
        s[n] = __builtin_amdgcn_mfma_f32_16x16x32_bf16(qf[ks], kf, s[n], 0, 0, 0);
      }

    const bool diag = (kv0 == qt);
    #pragma unroll
    for (int n = 0; n < 4; ++n)
      #pragma unroll
      for (int rr = 0; rr < 4; ++rr) {
        float v = s[n][rr] * 0.125f;   // 1/sqrt(64)
        if (diag) {
          int ql = wave * 16 + rg + rr;
          int kl = n * 16 + (lane & 15);
          if (kl > ql) v = -1e30f;
        }
        s[n][rr] = v;
      }

    // online softmax per q-row (each row lives on 16 lanes of one group, reg rr)
    #pragma unroll
    for (int rr = 0; rr < 4; ++rr) {
      float mx = fmaxf(fmaxf(s[0][rr], s[1][rr]), fmaxf(s[2][rr], s[3][rr]));
      mx = fmaxf(mx, __shfl_xor(mx, 1));
      mx = fmaxf(mx, __shfl_xor(mx, 2));
      mx = fmaxf(mx, __shfl_xor(mx, 4));
      mx = fmaxf(mx, __shfl_xor(mx, 8));
      float mnew  = fmaxf(mrun[rr], mx);
      float alpha = __expf(mrun[rr] - mnew);
      mrun[rr] = mnew;
      float sum = 0.f;
      #pragma unroll
      for (int n = 0; n < 4; ++n) {
        float p = __expf(s[n][rr] - mnew);
        s[n][rr] = p;
        sum += p;
      }
      sum += __shfl_xor(sum, 1);
      sum += __shfl_xor(sum, 2);
      sum += __shfl_xor(sum, 4);
      sum += __shfl_xor(sum, 8);
      lrun[rr] = lrun[rr] * alpha + sum;
      #pragma unroll
      for (int n = 0; n < 4; ++n) oacc[n][rr] *= alpha;
    }

    // stage P (wave-private region, no barrier needed)
    #pragma unroll
    for (int n = 0; n < 4; ++n)
      #pragma unroll
      for (int rr = 0; rr < 4; ++rr)
        Ps[wave][rg + rr][n * 16 + (lane & 15)] = f2bf(s[n][rr]);

    // O += P @ V
    #pragma unroll
    for (int ks = 0; ks < 2; ++ks) {
      bf16x8 pa = ld_bf8(&Ps[wave][lrow][ks * 32 + lk8]);
      #pragma unroll
      for (int n = 0; n < 4; ++n) {
        bf16x8 vf = ld_bf8(&Vs[n * 16 + lrow][ks * 32 + lk8]);
        oacc[n] = __builtin_amdgcn_mfma_f32_16x16x32_bf16(pa, vf, oacc[n], 0, 0, 0);
      }
    }
  }

  // normalize + write out[b][t][h*64 + d]  (bf16)
  #pragma unroll
  for (int rr = 0; rr < 4; ++rr) {
    float inv = 1.0f / lrun[rr];
    int t = qt + wave * 16 + rg + rr;
    size_t rowo = ((size_t)b * Tn + t) * Cn + h * Dn;
    #pragma unroll
    for (int n = 0; n < 4; ++n)
      outb[rowo + n * 16 + (lane & 15)] = f2bf(oacc[n][rr] * inv);
  }
}

extern "C" void kernel_launch(void* const* d_in, const int* in_sizes, int n_in,
                              void* d_out, int out_size, void* d_ws, size_t ws_size,
                              hipStream_t stream) {
  const float* x    = (const float*)d_in[0];
  const float* Wqkv = (const float*)d_in[1];
  const float* Wout = (const float*)d_in[2];
  float* y = (float*)d_out;

  // workspace layout (bf16/u16 elements)
  unsigned short* xb    = (unsigned short*)d_ws;
  unsigned short* wqkvb = xb    + (size_t)Bn * Tn * Cn;        // 8,388,608
  unsigned short* woutb = wqkvb + (size_t)3 * Cn * Cn;         // +3,145,728
  unsigned short* qkvb  = woutb + (size_t)Cn * Cn;             // +1,048,576
  unsigned short* attno = qkvb  + (size_t)Bn * Tn * 3 * Cn;    // +25,165,824
  // total = 92,274,688 bytes

  const int M = Bn * Tn;  // 8192

  {
    int n4 = (Bn * Tn * Cn) / 4;
    cvt_kernel<<<(n4 + 255) / 256, 256, 0, stream>>>(x, xb, n4);
  }
  {
    int n4 = (3 * Cn * Cn) / 4;
    cvt_kernel<<<(n4 + 255) / 256, 256, 0, stream>>>(Wqkv, wqkvb, n4);
  }
  {
    int n4 = (Cn * Cn) / 4;
    cvt_kernel<<<(n4 + 255) / 256, 256, 0, stream>>>(Wout, woutb, n4);
  }

  // qkv = x @ Wqkv^T : [8192 x 1024] @ [3072 x 1024]^T -> bf16 [8192 x 3072]
  gemm_bt<1><<<dim3(3 * Cn / 128, M / 128), 256, 0, stream>>>(xb, wqkvb, qkvb, M, 3 * Cn, Cn);

  // causal attention -> attno [8192 x 1024] bf16
  attn_kernel<<<dim3(Tn / 64, Bn * Hn), 256, 0, stream>>>(qkvb, attno);

  // y = attno @ Wout^T : f32 out
  gemm_bt<0><<<dim3(Cn / 128, M / 128), 256, 0, stream>>>(attno, woutb, y, M, Cn, Cn);

  (void)in_sizes; (void)n_in; (void)out_size; (void)ws_size;
}

// Round 3
// 481.328 us; speedup vs baseline: 1.7434x; 1.7434x over previous
//
#include <hip/hip_runtime.h>

// Problem constants: B=2, T=4096, C=1024, H=16, D=64
constexpr int Bn = 2;
constexpr int Tn = 4096;
constexpr int Cn = 1024;
constexpr int Hn = 16;
constexpr int Dn = 64;

typedef __bf16 bf16x8 __attribute__((ext_vector_type(8)));
typedef float f32x4 __attribute__((ext_vector_type(4)));
typedef unsigned short u16x8 __attribute__((ext_vector_type(8)));

__device__ __forceinline__ unsigned short f2bf(float f) {
  unsigned int u = __float_as_uint(f);
  u += 0x7FFF + ((u >> 16) & 1);   // round-to-nearest-even
  return (unsigned short)(u >> 16);
}

__device__ __forceinline__ bf16x8 ld_bf8(const unsigned short* p) {
  return __builtin_bit_cast(bf16x8, *(const u16x8*)p);
}

// ---------------- f32 -> bf16 cast (vectorized) ----------------
__global__ void cvt_kernel(const float* __restrict__ in, unsigned short* __restrict__ out, int n4) {
  int i = blockIdx.x * blockDim.x + threadIdx.x;
  if (i >= n4) return;
  float4 v = ((const float4*)in)[i];
  ushort4 o;
  o.x = f2bf(v.x); o.y = f2bf(v.y); o.z = f2bf(v.z); o.w = f2bf(v.w);
  ((ushort4*)out)[i] = o;
}

// ---------------- GEMM: C[M][N] = A[M][K] @ B[N][K]^T (unchanged, known-good) ----------------
template<int OUT_BF16>
__global__ __launch_bounds__(256) void gemm_bt(const unsigned short* __restrict__ A,
                                               const unsigned short* __restrict__ Bm,
                                               void* __restrict__ Cout,
                                               int M, int N, int K) {
  __shared__ __align__(16) unsigned short As[128][64];
  __shared__ __align__(16) unsigned short Bs[128][64];
  const int tid  = threadIdx.x;
  const int wave = tid >> 6;
  const int lane = tid & 63;
  const int wr   = (wave >> 1) * 64;
  const int wc   = (wave & 1) * 64;
  const int lrow = lane & 15;
  const int lk8  = (lane >> 4) << 3;
  const int row0 = blockIdx.y * 128;
  const int col0 = blockIdx.x * 128;

  f32x4 acc[4][4];
  #pragma unroll
  for (int i = 0; i < 4; ++i)
    #pragma unroll
    for (int j = 0; j < 4; ++j)
      acc[i][j] = (f32x4){0.f, 0.f, 0.f, 0.f};

  for (int k0 = 0; k0 < K; k0 += 64) {
    const unsigned short* Ag = A  + (size_t)row0 * K + k0;
    const unsigned short* Bg = Bm + (size_t)col0 * K + k0;
    #pragma unroll
    for (int i = 0; i < 4; ++i) {
      int flat = (i * 256 + tid) * 8;
      int r = flat >> 6, c = flat & 63;
      __builtin_amdgcn_global_load_lds((const __attribute__((address_space(1))) void*)(Ag + (size_t)r * K + c),
                                       (__attribute__((address_space(3))) void*)(&As[r][c]), 16, 0, 0);
    }
    #pragma unroll
    for (int i = 0; i < 4; ++i) {
      int flat = (i * 256 + tid) * 8;
      int r = flat >> 6, c = flat & 63;
      __builtin_amdgcn_global_load_lds((const __attribute__((address_space(1))) void*)(Bg + (size_t)r * K + c),
                                       (__attribute__((address_space(3))) void*)(&Bs[r][c]), 16, 0, 0);
    }
    __syncthreads();

    #pragma unroll
    for (int ks = 0; ks < 2; ++ks) {
      bf16x8 af[4], bfr[4];
      #pragma unroll
      for (int i = 0; i < 4; ++i) af[i]  = ld_bf8(&As[wr + i * 16 + lrow][ks * 32 + lk8]);
      #pragma unroll
      for (int j = 0; j < 4; ++j) bfr[j] = ld_bf8(&Bs[wc + j * 16 + lrow][ks * 32 + lk8]);
      #pragma unroll
      for (int i = 0; i < 4; ++i)
        #pragma unroll
        for (int j = 0; j < 4; ++j)
          acc[i][j] = __builtin_amdgcn_mfma_f32_16x16x32_bf16(af[i], bfr[j], acc[i][j], 0, 0, 0);
    }
    __syncthreads();
  }

  const int rg = (lane >> 4) * 4;
  const int cl = lane & 15;
  #pragma unroll
  for (int i = 0; i < 4; ++i)
    #pragma unroll
    for (int j = 0; j < 4; ++j)
      #pragma unroll
      for (int rr = 0; rr < 4; ++rr) {
        int gm = row0 + wr + i * 16 + rg + rr;
        int gn = col0 + wc + j * 16 + cl;
        float v = acc[i][j][rr];
        if (OUT_BF16) ((unsigned short*)Cout)[(size_t)gm * N + gn] = f2bf(v);
        else          ((float*)Cout)[(size_t)gm * N + gn] = v;
      }
}

// ---------------- Causal flash attention ----------------
// grid = 2048 blocks, block = 256 (4 waves x 16 q-rows). KVBLK=64, D=64.
// Double-buffered K/V, 2-phase pipeline: issue stage(t+1) -> compute(t) ->
// write V regs(t+1) -> syncthreads.
// Ks[buf]: row-major [kv][64], slot (8 u16) XOR-swizzled by kv&7; swizzle applied
//   at the GLOBAL source so global_load_lds keeps a linear LDS dest.
// Vt[buf]: transposed [d][kv], slot swizzled by (kv>>3)^((d>>3)&7):
//   u16 idx = d*64 + ((kv>>3)^((d>>3)&7))*8 + (kv&7).
//   Writes: 2-way (free). Reads (b128): 8-way (floor for 128B rows).
// Ps: [wave][16 rows][8 slots], slot XOR-swizzled by row&7.
__global__ __launch_bounds__(256) void attn_kernel(const unsigned short* __restrict__ qkv,
                                                   unsigned short* __restrict__ outb) {
  __shared__ __align__(16) unsigned short Ks[2][4096];
  __shared__ __align__(16) unsigned short Vt[2][4096];
  __shared__ __align__(16) unsigned short Ps[4][1024];

  const int tid  = threadIdx.x;
  const int wave = tid >> 6;
  const int lane = tid & 63;
  const int cl   = lane & 15;        // fragment row/col index
  const int g    = lane >> 4;        // lane group 0..3
  const int lk8  = g << 3;
  const int rg   = g * 4;

  // XCD-aware swizzle (bijective, 2048 % 8 == 0): 4 full (b,h) groups per XCD,
  // heavy (large-qt) blocks first within each group.
  const int orig = blockIdx.y * gridDim.x + blockIdx.x;   // 0..2047
  const int cid  = (orig & 7) * 256 + (orig >> 3);
  const int qt   = (63 - (cid & 63)) * 64;
  const int bh   = cid >> 6;
  const int b    = bh >> 4;
  const int h    = bh & 15;

  const unsigned short* qb = qkv + (size_t)b * Tn * (3 * Cn) + h * Dn;
  const unsigned short* kb = qb + Cn;
  const unsigned short* vb = qb + 2 * Cn;

  // Q fragments (A layout: row = lane&15, k = (lane>>4)*8 + j)
  bf16x8 qf[2];
  {
    const unsigned short* qr = qb + (size_t)(qt + wave * 16 + cl) * (3 * Cn) + lk8;
    qf[0] = ld_bf8(qr);
    qf[1] = ld_bf8(qr + 32);
  }

  f32x4 oacc[4];
  #pragma unroll
  for (int n = 0; n < 4; ++n) oacc[n] = (f32x4){0.f, 0.f, 0.f, 0.f};
  float mrun[4] = {-1e30f, -1e30f, -1e30f, -1e30f};
  float lrun[4] = {0.f, 0.f, 0.f, 0.f};

  // ---- prologue: stage tile 0 into buffer 0 ----
  #pragma unroll
  for (int i = 0; i < 2; ++i) {
    const int flat = i * 256 + tid;            // 0..511
    const int kr   = flat >> 3;                // kv row 0..63
    const int cg   = flat & 7;                 // 8-u16 column group
    const int ksl  = cg ^ (kr & 7);            // pre-swizzled global slot
    __builtin_amdgcn_global_load_lds(
        (const __attribute__((address_space(1))) void*)(kb + (size_t)kr * (3 * Cn) + ksl * 8),
        (__attribute__((address_space(3))) void*)(&Ks[0][flat * 8]), 16, 0, 0);
    u16x8 vv = *(const u16x8*)(vb + (size_t)kr * (3 * Cn) + cg * 8);
    #pragma unroll
    for (int j = 0; j < 8; ++j)
      Vt[0][(cg * 8 + j) * 64 + (((kr >> 3) ^ cg) << 3) + (kr & 7)] = vv[j];
  }
  __syncthreads();

  const int nkv = qt / 64 + 1;
  for (int kt = 0; kt < nkv; ++kt) {
    const int kv0 = kt * 64;
    const int cur = kt & 1;
    const int nb  = cur ^ 1;
    const bool pre = (kt + 1 < nkv);

    // ---- phase A: issue next tile's staging (loads in flight during compute) ----
    u16x8 vreg[2];
    if (pre) {
      const int kv1 = kv0 + 64;
      #pragma unroll
      for (int i = 0; i < 2; ++i) {
        const int flat = i * 256 + tid;
        const int kr   = flat >> 3;
        const int cg   = flat & 7;
        const int ksl  = cg ^ (kr & 7);
        __builtin_amdgcn_global_load_lds(
            (const __attribute__((address_space(1))) void*)(kb + (size_t)(kv1 + kr) * (3 * Cn) + ksl * 8),
            (__attribute__((address_space(3))) void*)(&Ks[nb][flat * 8]), 16, 0, 0);
        vreg[i] = *(const u16x8*)(vb + (size_t)(kv1 + kr) * (3 * Cn) + cg * 8);
      }
    }

    // ---- phase B: compute tile kt ----
    // S = Q @ K^T
    f32x4 s[4];
    #pragma unroll
    for (int n = 0; n < 4; ++n) s[n] = (f32x4){0.f, 0.f, 0.f, 0.f};
    __builtin_amdgcn_s_setprio(1);
    #pragma unroll
    for (int n = 0; n < 4; ++n)
      #pragma unroll
      for (int ks = 0; ks < 2; ++ks) {
        const int row = n * 16 + cl;
        bf16x8 kf = ld_bf8(&Ks[cur][row * 64 + (((ks * 4 + g) ^ (cl & 7)) << 3)]);
        s[n] = __builtin_amdgcn_mfma_f32_16x16x32_bf16(qf[ks], kf, s[n], 0, 0, 0);
      }
    __builtin_amdgcn_s_setprio(0);

    // scale + causal mask
    const bool diag = (kv0 == qt);
    #pragma unroll
    for (int n = 0; n < 4; ++n)
      #pragma unroll
      for (int rr = 0; rr < 4; ++rr) {
        float v = s[n][rr] * 0.125f;   // 1/sqrt(64)
        if (diag) {
          int ql = wave * 16 + rg + rr;
          int kl = n * 16 + cl;
          if (kl > ql) v = -1e30f;
        }
        s[n][rr] = v;
      }

    // online softmax per q-row
    #pragma unroll
    for (int rr = 0; rr < 4; ++rr) {
      float mx = fmaxf(fmaxf(s[0][rr], s[1][rr]), fmaxf(s[2][rr], s[3][rr]));
      mx = fmaxf(mx, __shfl_xor(mx, 1));
      mx = fmaxf(mx, __shfl_xor(mx, 2));
      mx = fmaxf(mx, __shfl_xor(mx, 4));
      mx = fmaxf(mx, __shfl_xor(mx, 8));
      float mnew  = fmaxf(mrun[rr], mx);
      float alpha = __expf(mrun[rr] - mnew);
      mrun[rr] = mnew;
      float sum = 0.f;
      #pragma unroll
      for (int n = 0; n < 4; ++n) {
        float p = __expf(s[n][rr] - mnew);
        s[n][rr] = p;
        sum += p;
      }
      sum += __shfl_xor(sum, 1);
      sum += __shfl_xor(sum, 2);
      sum += __shfl_xor(sum, 4);
      sum += __shfl_xor(sum, 8);
      lrun[rr] = lrun[rr] * alpha + sum;
      #pragma unroll
      for (int n = 0; n < 4; ++n) oacc[n][rr] *= alpha;
    }

    // stage P (wave-private, slot XOR-swizzled by row&7)
    #pragma unroll
    for (int n = 0; n < 4; ++n)
      #pragma unroll
      for (int rr = 0; rr < 4; ++rr) {
        const int row  = rg + rr;
        const int slot = n * 2 + (cl >> 3);
        Ps[wave][row * 64 + ((slot ^ (row & 7)) << 3) + (cl & 7)] = f2bf(s[n][rr]);
      }

    // O += P @ V   (V read from swizzled transposed layout)
    #pragma unroll
    for (int ks = 0; ks < 2; ++ks) {
      bf16x8 pa = ld_bf8(&Ps[wave][cl * 64 + (((ks * 4 + g) ^ (cl & 7)) << 3)]);
      __builtin_amdgcn_s_setprio(1);
      #pragma unroll
      for (int n = 0; n < 4; ++n) {
        const int dr = n * 16 + cl;
        bf16x8 vf = ld_bf8(&Vt[cur][dr * 64 + (((ks * 4 + g) ^ ((dr >> 3) & 7)) << 3)]);
        oacc[n] = __builtin_amdgcn_mfma_f32_16x16x32_bf16(pa, vf, oacc[n], 0, 0, 0);
      }
      __builtin_amdgcn_s_setprio(0);
    }

    // ---- phase C: write next tile's V regs to LDS (global data arrived during compute) ----
    if (pre) {
      #pragma unroll
      for (int i = 0; i < 2; ++i) {
        const int flat = i * 256 + tid;
        const int kr   = flat >> 3;
        const int cg   = flat & 7;
        #pragma unroll
        for (int j = 0; j < 8; ++j)
          Vt[nb][(cg * 8 + j) * 64 + (((kr >> 3) ^ cg) << 3) + (kr & 7)] = vreg[i][j];
      }
    }
    __syncthreads();   // drains vmcnt (K arrival) + lgkm; gates buffer reuse
  }

  // ---- normalize + write out[b][t][h*64 + d] (bf16) ----
  #pragma unroll
  for (int rr = 0; rr < 4; ++rr) {
    float inv = 1.0f / lrun[rr];
    int t = qt + wave * 16 + rg + rr;
    size_t rowo = ((size_t)b * Tn + t) * Cn + h * Dn;
    #pragma unroll
    for (int n = 0; n < 4; ++n)
      outb[rowo + n * 16 + cl] = f2bf(oacc[n][rr] * inv);
  }
}

extern "C" void kernel_launch(void* const* d_in, const int* in_sizes, int n_in,
                              void* d_out, int out_size, void* d_ws, size_t ws_size,
                              hipStream_t stream) {
  const float* x    = (const float*)d_in[0];
  const float* Wqkv = (const float*)d_in[1];
  const float* Wout = (const float*)d_in[2];
  float* y = (float*)d_out;

  unsigned short* xb    = (unsigned short*)d_ws;
  unsigned short* wqkvb = xb    + (size_t)Bn * Tn * Cn;
  unsigned short* woutb = wqkvb + (size_t)3 * Cn * Cn;
  unsigned short* qkvb  = woutb + (size_t)Cn * Cn;
  unsigned short* attno = qkvb  + (size_t)Bn * Tn * 3 * Cn;

  const int M = Bn * Tn;  // 8192

  {
    int n4 = (Bn * Tn * Cn) / 4;
    cvt_kernel<<<(n4 + 255) / 256, 256, 0, stream>>>(x, xb, n4);
  }
  {
    int n4 = (3 * Cn * Cn) / 4;
    cvt_kernel<<<(n4 + 255) / 256, 256, 0, stream>>>(Wqkv, wqkvb, n4);
  }
  {
    int n4 = (Cn * Cn) / 4;
    cvt_kernel<<<(n4 + 255) / 256, 256, 0, stream>>>(Wout, woutb, n4);
  }

  gemm_bt<1><<<dim3(3 * Cn / 128, M / 128), 256, 0, stream>>>(xb, wqkvb, qkvb, M, 3 * Cn, Cn);
  attn_kernel<<<dim3(Tn / 64, Bn * Hn), 256, 0, stream>>>(qkvb, attno);
  gemm_bt<0><<<dim3(Cn / 128, M / 128), 256, 0, stream>>>(attno, woutb, y, M, Cn, Cn);

  (void)in_sizes; (void)n_in; (void)out_size; (void)ws_size;
}

// Round 4
// 448.565 us; speedup vs baseline: 1.8707x; 1.0730x over previous
//
#include <hip/hip_runtime.h>

// Problem constants: B=2, T=4096, C=1024, H=16, D=64
constexpr int Bn = 2;
constexpr int Tn = 4096;
constexpr int Cn = 1024;
constexpr int Hn = 16;
constexpr int Dn = 64;

typedef __bf16 bf16x8 __attribute__((ext_vector_type(8)));
typedef float f32x4 __attribute__((ext_vector_type(4)));
typedef unsigned short u16x8 __attribute__((ext_vector_type(8)));

__device__ __forceinline__ unsigned short f2bf(float f) {
  unsigned int u = __float_as_uint(f);
  u += 0x7FFF + ((u >> 16) & 1);   // round-to-nearest-even
  return (unsigned short)(u >> 16);
}

__device__ __forceinline__ bf16x8 ld_bf8(const unsigned short* p) {
  return __builtin_bit_cast(bf16x8, *(const u16x8*)p);
}

// ---------------- f32 -> bf16 cast (vectorized) ----------------
__global__ void cvt_kernel(const float* __restrict__ in, unsigned short* __restrict__ out, int n4) {
  int i = blockIdx.x * blockDim.x + threadIdx.x;
  if (i >= n4) return;
  float4 v = ((const float4*)in)[i];
  ushort4 o;
  o.x = f2bf(v.x); o.y = f2bf(v.y); o.z = f2bf(v.z); o.w = f2bf(v.w);
  ((ushort4*)out)[i] = o;
}

// ---------------- GEMM: C[M][N] = A[M][K] @ B[N][K]^T (unchanged, known-good) ----------------
template<int OUT_BF16>
__global__ __launch_bounds__(256) void gemm_bt(const unsigned short* __restrict__ A,
                                               const unsigned short* __restrict__ Bm,
                                               void* __restrict__ Cout,
                                               int M, int N, int K) {
  __shared__ __align__(16) unsigned short As[128][64];
  __shared__ __align__(16) unsigned short Bs[128][64];
  const int tid  = threadIdx.x;
  const int wave = tid >> 6;
  const int lane = tid & 63;
  const int wr   = (wave >> 1) * 64;
  const int wc   = (wave & 1) * 64;
  const int lrow = lane & 15;
  const int lk8  = (lane >> 4) << 3;
  const int row0 = blockIdx.y * 128;
  const int col0 = blockIdx.x * 128;

  f32x4 acc[4][4];
  #pragma unroll
  for (int i = 0; i < 4; ++i)
    #pragma unroll
    for (int j = 0; j < 4; ++j)
      acc[i][j] = (f32x4){0.f, 0.f, 0.f, 0.f};

  for (int k0 = 0; k0 < K; k0 += 64) {
    const unsigned short* Ag = A  + (size_t)row0 * K + k0;
    const unsigned short* Bg = Bm + (size_t)col0 * K + k0;
    #pragma unroll
    for (int i = 0; i < 4; ++i) {
      int flat = (i * 256 + tid) * 8;
      int r = flat >> 6, c = flat & 63;
      __builtin_amdgcn_global_load_lds((const __attribute__((address_space(1))) void*)(Ag + (size_t)r * K + c),
                                       (__attribute__((address_space(3))) void*)(&As[r][c]), 16, 0, 0);
    }
    #pragma unroll
    for (int i = 0; i < 4; ++i) {
      int flat = (i * 256 + tid) * 8;
      int r = flat >> 6, c = flat & 63;
      __builtin_amdgcn_global_load_lds((const __attribute__((address_space(1))) void*)(Bg + (size_t)r * K + c),
                                       (__attribute__((address_space(3))) void*)(&Bs[r][c]), 16, 0, 0);
    }
    __syncthreads();

    #pragma unroll
    for (int ks = 0; ks < 2; ++ks) {
      bf16x8 af[4], bfr[4];
      #pragma unroll
      for (int i = 0; i < 4; ++i) af[i]  = ld_bf8(&As[wr + i * 16 + lrow][ks * 32 + lk8]);
      #pragma unroll
      for (int j = 0; j < 4; ++j) bfr[j] = ld_bf8(&Bs[wc + j * 16 + lrow][ks * 32 + lk8]);
      #pragma unroll
      for (int i = 0; i < 4; ++i)
        #pragma unroll
        for (int j = 0; j < 4; ++j)
          acc[i][j] = __builtin_amdgcn_mfma_f32_16x16x32_bf16(af[i], bfr[j], acc[i][j], 0, 0, 0);
    }
    __syncthreads();
  }

  const int rg = (lane >> 4) * 4;
  const int cl = lane & 15;
  #pragma unroll
  for (int i = 0; i < 4; ++i)
    #pragma unroll
    for (int j = 0; j < 4; ++j)
      #pragma unroll
      for (int rr = 0; rr < 4; ++rr) {
        int gm = row0 + wr + i * 16 + rg + rr;
        int gn = col0 + wc + j * 16 + cl;
        float v = acc[i][j][rr];
        if (OUT_BF16) ((unsigned short*)Cout)[(size_t)gm * N + gn] = f2bf(v);
        else          ((float*)Cout)[(size_t)gm * N + gn] = v;
      }
}

// ---------------- V transpose: qkv V-part -> vT[b][h][d][T] ----------------
// grid (T/64, B*H), block 256. LDS 64x64 u16 tile, chunk-swizzled so both the
// staging (linear, global_load_lds w/ pre-swizzled source) and the transposed
// read (per-instr: 32 banks, 2 same-word lanes) are conflict-free.
__global__ __launch_bounds__(256) void vtrans_kernel(const unsigned short* __restrict__ qkv,
                                                     unsigned short* __restrict__ vT) {
  __shared__ __align__(16) unsigned short L[64 * 64];
  const int tid = threadIdx.x;
  const int t0  = blockIdx.x * 64;
  const int bh  = blockIdx.y;
  const int b   = bh >> 4;
  const int h   = bh & 15;
  const unsigned short* src = qkv + (size_t)b * Tn * (3 * Cn) + 2 * Cn + h * Dn;

  #pragma unroll
  for (int i = 0; i < 2; ++i) {
    int flat = i * 256 + tid;          // 0..511
    int t = flat >> 3, c = flat & 7;
    int cs = c ^ ((t >> 3) & 7);       // pre-swizzled source chunk
    __builtin_amdgcn_global_load_lds(
        (const __attribute__((address_space(1))) void*)(src + (size_t)(t0 + t) * (3 * Cn) + cs * 8),
        (__attribute__((address_space(3))) void*)(&L[flat * 8]), 16, 0, 0);
  }
  __syncthreads();

  #pragma unroll
  for (int i = 0; i < 2; ++i) {
    int flat = i * 256 + tid;
    int d = flat >> 3, tc = flat & 7;
    u16x8 o;
    #pragma unroll
    for (int j = 0; j < 8; ++j) {
      int t = tc * 8 + j;
      // element V[t][d] lives at LDS[t][ ((d>>3)^((t>>3)&7))*8 + (d&7) ]
      o[j] = L[t * 64 + (((d >> 3) ^ ((t >> 3) & 7)) << 3) + (d & 7)];
    }
    *(u16x8*)(vT + ((size_t)bh * 64 + d) * Tn + t0 + tc * 8) = o;
  }
}

// ---------------- Causal flash attention ----------------
// grid = 2048 blocks, block = 256 (4 waves x 16 q-rows). KVBLK=64, D=64.
// K and V^T both staged via global_load_lds (linear LDS dest, pre-swizzled
// global source), double-buffered; 2-phase pipeline (issue t+1 -> compute t).
// Ks[buf]: [kv][64], 16B slot XOR-swizzled by kv&7.
// Vs[buf]: [d][64kv], 16B slot XOR-swizzled by d&7 (source = vT, rows contiguous).
// Ps:      [wave][16 rows][8 slots], slot XOR-swizzled by row&7.
// Scale 1/8 folded into Q (exact exponent shift in bf16).
__global__ __launch_bounds__(256) void attn_kernel(const unsigned short* __restrict__ qkv,
                                                   const unsigned short* __restrict__ vT,
                                                   unsigned short* __restrict__ outb) {
  __shared__ __align__(16) unsigned short Ks[2][4096];
  __shared__ __align__(16) unsigned short Vs[2][4096];
  __shared__ __align__(16) unsigned short Ps[4][1024];

  const int tid  = threadIdx.x;
  const int wave = tid >> 6;
  const int lane = tid & 63;
  const int cl   = lane & 15;        // fragment row/col index
  const int g    = lane >> 4;        // lane group 0..3
  const int lk8  = g << 3;
  const int rg   = g * 4;

  // XCD-aware swizzle (bijective, 2048 % 8 == 0); heavy (large-qt) blocks first.
  const int orig = blockIdx.y * gridDim.x + blockIdx.x;   // 0..2047
  const int cid  = (orig & 7) * 256 + (orig >> 3);
  const int qt   = (63 - (cid & 63)) * 64;
  const int bh   = cid >> 6;
  const int b    = bh >> 4;
  const int h    = bh & 15;

  const unsigned short* qb  = qkv + (size_t)b * Tn * (3 * Cn) + h * Dn;
  const unsigned short* kb  = qb + Cn;
  const unsigned short* vtb = vT + (size_t)bh * Dn * Tn;

  // Q fragments (A layout: row = lane&15, k = (lane>>4)*8 + j), pre-scaled by 1/8
  bf16x8 qf[2];
  {
    const unsigned short* qr = qb + (size_t)(qt + wave * 16 + cl) * (3 * Cn) + lk8;
    qf[0] = ld_bf8(qr);
    qf[1] = ld_bf8(qr + 32);
    #pragma unroll
    for (int j = 0; j < 8; ++j) {
      qf[0][j] = qf[0][j] * (__bf16)0.125f;
      qf[1][j] = qf[1][j] * (__bf16)0.125f;
    }
  }

  f32x4 oacc[4];
  #pragma unroll
  for (int n = 0; n < 4; ++n) oacc[n] = (f32x4){0.f, 0.f, 0.f, 0.f};
  float mrun[4] = {-1e30f, -1e30f, -1e30f, -1e30f};
  float lrun[4] = {0.f, 0.f, 0.f, 0.f};

  // ---- prologue: stage tile 0 into buffer 0 ----
  #pragma unroll
  for (int i = 0; i < 2; ++i) {
    const int flat = i * 256 + tid;            // 0..511
    const int r    = flat >> 3;                // K: kv row | V: d row
    const int cg   = flat & 7;
    const int sw   = cg ^ (r & 7);
    __builtin_amdgcn_global_load_lds(
        (const __attribute__((address_space(1))) void*)(kb + (size_t)r * (3 * Cn) + sw * 8),
        (__attribute__((address_space(3))) void*)(&Ks[0][flat * 8]), 16, 0, 0);
    __builtin_amdgcn_global_load_lds(
        (const __attribute__((address_space(1))) void*)(vtb + (size_t)r * Tn + sw * 8),
        (__attribute__((address_space(3))) void*)(&Vs[0][flat * 8]), 16, 0, 0);
  }
  __syncthreads();

  const int nkv = qt / 64 + 1;
  for (int kt = 0; kt < nkv; ++kt) {
    const int kv0 = kt * 64;
    const int cur = kt & 1;
    const int nb  = cur ^ 1;
    const bool pre = (kt + 1 < nkv);

    // ---- phase A: issue next tile's staging (in flight during compute) ----
    if (pre) {
      const int kv1 = kv0 + 64;
      #pragma unroll
      for (int i = 0; i < 2; ++i) {
        const int flat = i * 256 + tid;
        const int r    = flat >> 3;
        const int cg   = flat & 7;
        const int sw   = cg ^ (r & 7);
        __builtin_amdgcn_global_load_lds(
            (const __attribute__((address_space(1))) void*)(kb + (size_t)(kv1 + r) * (3 * Cn) + sw * 8),
            (__attribute__((address_space(3))) void*)(&Ks[nb][flat * 8]), 16, 0, 0);
        __builtin_amdgcn_global_load_lds(
            (const __attribute__((address_space(1))) void*)(vtb + (size_t)r * Tn + kv1 + sw * 8),
            (__attribute__((address_space(3))) void*)(&Vs[nb][flat * 8]), 16, 0, 0);
      }
    }

    // ---- phase B: compute tile kt ----
    // S = Q @ K^T
    f32x4 s[4];
    #pragma unroll
    for (int n = 0; n < 4; ++n) s[n] = (f32x4){0.f, 0.f, 0.f, 0.f};
    __builtin_amdgcn_s_setprio(1);
    #pragma unroll
    for (int n = 0; n < 4; ++n)
      #pragma unroll
      for (int ks = 0; ks < 2; ++ks) {
        bf16x8 kf = ld_bf8(&Ks[cur][(n * 16 + cl) * 64 + (((ks * 4 + g) ^ (cl & 7)) << 3)]);
        s[n] = __builtin_amdgcn_mfma_f32_16x16x32_bf16(qf[ks], kf, s[n], 0, 0, 0);
      }
    __builtin_amdgcn_s_setprio(0);

    // causal mask (scale already folded into Q)
    const bool diag = (kv0 == qt);
    if (diag) {
      #pragma unroll
      for (int n = 0; n < 4; ++n)
        #pragma unroll
        for (int rr = 0; rr < 4; ++rr) {
          int ql = wave * 16 + rg + rr;
          int kl = n * 16 + cl;
          if (kl > ql) s[n][rr] = -1e30f;
        }
    }

    // online softmax per q-row
    #pragma unroll
    for (int rr = 0; rr < 4; ++rr) {
      float mx = fmaxf(fmaxf(s[0][rr], s[1][rr]), fmaxf(s[2][rr], s[3][rr]));
      mx = fmaxf(mx, __shfl_xor(mx, 1));
      mx = fmaxf(mx, __shfl_xor(mx, 2));
      mx = fmaxf(mx, __shfl_xor(mx, 4));
      mx = fmaxf(mx, __shfl_xor(mx, 8));
      float mnew  = fmaxf(mrun[rr], mx);
      float alpha = __expf(mrun[rr] - mnew);
      mrun[rr] = mnew;
      float sum = 0.f;
      #pragma unroll
      for (int n = 0; n < 4; ++n) {
        float p = __expf(s[n][rr] - mnew);
        s[n][rr] = p;
        sum += p;
      }
      sum += __shfl_xor(sum, 1);
      sum += __shfl_xor(sum, 2);
      sum += __shfl_xor(sum, 4);
      sum += __shfl_xor(sum, 8);
      lrun[rr] = lrun[rr] * alpha + sum;
      #pragma unroll
      for (int n = 0; n < 4; ++n) oacc[n][rr] *= alpha;
    }

    // stage P (wave-private, slot XOR-swizzled by row&7)
    #pragma unroll
    for (int n = 0; n < 4; ++n)
      #pragma unroll
      for (int rr = 0; rr < 4; ++rr) {
        const int row  = rg + rr;
        const int slot = n * 2 + (cl >> 3);
        Ps[wave][row * 64 + ((slot ^ (row & 7)) << 3) + (cl & 7)] = f2bf(s[n][rr]);
      }

    // O += P @ V   (B-fragment = V^T rows, 2-way conflict-free)
    #pragma unroll
    for (int ks = 0; ks < 2; ++ks) {
      bf16x8 pa = ld_bf8(&Ps[wave][cl * 64 + (((ks * 4 + g) ^ (cl & 7)) << 3)]);
      __builtin_amdgcn_s_setprio(1);
      #pragma unroll
      for (int n = 0; n < 4; ++n) {
        bf16x8 vf = ld_bf8(&Vs[cur][(n * 16 + cl) * 64 + (((ks * 4 + g) ^ (cl & 7)) << 3)]);
        oacc[n] = __builtin_amdgcn_mfma_f32_16x16x32_bf16(pa, vf, oacc[n], 0, 0, 0);
      }
      __builtin_amdgcn_s_setprio(0);
    }

    __syncthreads();   // drains vmcnt (next tile's K/V arrival); gates buffer reuse
  }

  // ---- normalize + write out[b][t][h*64 + d] (bf16) ----
  #pragma unroll
  for (int rr = 0; rr < 4; ++rr) {
    float inv = 1.0f / lrun[rr];
    int t = qt + wave * 16 + rg + rr;
    size_t rowo = ((size_t)b * Tn + t) * Cn + h * Dn;
    #pragma unroll
    for (int n = 0; n < 4; ++n)
      outb[rowo + n * 16 + cl] = f2bf(oacc[n][rr] * inv);
  }
}

extern "C" void kernel_launch(void* const* d_in, const int* in_sizes, int n_in,
                              void* d_out, int out_size, void* d_ws, size_t ws_size,
                              hipStream_t stream) {
  const float* x    = (const float*)d_in[0];
  const float* Wqkv = (const float*)d_in[1];
  const float* Wout = (const float*)d_in[2];
  float* y = (float*)d_out;

  unsigned short* xb    = (unsigned short*)d_ws;               // later reused as vT (same size!)
  unsigned short* wqkvb = xb    + (size_t)Bn * Tn * Cn;
  unsigned short* woutb = wqkvb + (size_t)3 * Cn * Cn;
  unsigned short* qkvb  = woutb + (size_t)Cn * Cn;
  unsigned short* attno = qkvb  + (size_t)Bn * Tn * 3 * Cn;

  const int M = Bn * Tn;  // 8192

  {
    int n4 = (Bn * Tn * Cn) / 4;
    cvt_kernel<<<(n4 + 255) / 256, 256, 0, stream>>>(x, xb, n4);
  }
  {
    int n4 = (3 * Cn * Cn) / 4;
    cvt_kernel<<<(n4 + 255) / 256, 256, 0, stream>>>(Wqkv, wqkvb, n4);
  }
  {
    int n4 = (Cn * Cn) / 4;
    cvt_kernel<<<(n4 + 255) / 256, 256, 0, stream>>>(Wout, woutb, n4);
  }

  gemm_bt<1><<<dim3(3 * Cn / 128, M / 128), 256, 0, stream>>>(xb, wqkvb, qkvb, M, 3 * Cn, Cn);

  // xb is dead after gemm1 -> reuse as vT[b][h][d][T]
  unsigned short* vT = xb;
  vtrans_kernel<<<dim3(Tn / 64, Bn * Hn), 256, 0, stream>>>(qkvb, vT);

  attn_kernel<<<dim3(Tn / 64, Bn * Hn), 256, 0, stream>>>(qkvb, vT, attno);

  gemm_bt<0><<<dim3(Cn / 128, M / 128), 256, 0, stream>>>(attno, woutb, y, M, Cn, Cn);

  (void)in_sizes; (void)n_in; (void)out_size; (void)ws_size;
}

// Round 5
// 413.021 us; speedup vs baseline: 2.0317x; 1.0861x over previous
//
#include <hip/hip_runtime.h>

// Problem constants: B=2, T=4096, C=1024, H=16, D=64
constexpr int Bn = 2;
constexpr int Tn = 4096;
constexpr int Cn = 1024;
constexpr int Hn = 16;
constexpr int Dn = 64;

typedef __bf16 bf16x8 __attribute__((ext_vector_type(8)));
typedef float f32x4 __attribute__((ext_vector_type(4)));
typedef unsigned short u16x8 __attribute__((ext_vector_type(8)));

__device__ __forceinline__ unsigned short f2bf(float f) {
  unsigned int u = __float_as_uint(f);
  u += 0x7FFF + ((u >> 16) & 1);   // round-to-nearest-even
  return (unsigned short)(u >> 16);
}

__device__ __forceinline__ unsigned short f2bf_hw(float f) {
  return __builtin_bit_cast(unsigned short, (__bf16)f);   // HW cvt, RNE
}

__device__ __forceinline__ bf16x8 ld_bf8(const unsigned short* p) {
  return __builtin_bit_cast(bf16x8, *(const u16x8*)p);
}

// ---------------- f32 -> bf16 cast (vectorized) ----------------
__global__ void cvt_kernel(const float* __restrict__ in, unsigned short* __restrict__ out, int n4) {
  int i = blockIdx.x * blockDim.x + threadIdx.x;
  if (i >= n4) return;
  float4 v = ((const float4*)in)[i];
  ushort4 o;
  o.x = f2bf(v.x); o.y = f2bf(v.y); o.z = f2bf(v.z); o.w = f2bf(v.w);
  ((ushort4*)out)[i] = o;
}

// ---------------- GEMM: C[M][N] = A[M][K] @ B[N][K]^T ----------------
// 128x128 tile; XCD-aware bijective block swizzle (requires nwg % 8 == 0):
// consecutive cid on one XCD sweep cols of the same row-panel (A panel L2-resident).
template<int OUT_BF16>
__global__ __launch_bounds__(256) void gemm_bt(const unsigned short* __restrict__ A,
                                               const unsigned short* __restrict__ Bm,
                                               void* __restrict__ Cout,
                                               int M, int N, int K) {
  __shared__ __align__(16) unsigned short As[128][64];
  __shared__ __align__(16) unsigned short Bs[128][64];
  const int tid  = threadIdx.x;
  const int wave = tid >> 6;
  const int lane = tid & 63;
  const int wr   = (wave >> 1) * 64;
  const int wc   = (wave & 1) * 64;
  const int lrow = lane & 15;
  const int lk8  = (lane >> 4) << 3;

  const int nbx  = gridDim.x;
  const int nwg  = nbx * gridDim.y;
  const int orig = blockIdx.y * nbx + blockIdx.x;
  const int cid  = (orig & 7) * (nwg >> 3) + (orig >> 3);
  const int row0 = (cid / nbx) * 128;
  const int col0 = (cid % nbx) * 128;

  f32x4 acc[4][4];
  #pragma unroll
  for (int i = 0; i < 4; ++i)
    #pragma unroll
    for (int j = 0; j < 4; ++j)
      acc[i][j] = (f32x4){0.f, 0.f, 0.f, 0.f};

  for (int k0 = 0; k0 < K; k0 += 64) {
    const unsigned short* Ag = A  + (size_t)row0 * K + k0;
    const unsigned short* Bg = Bm + (size_t)col0 * K + k0;
    #pragma unroll
    for (int i = 0; i < 4; ++i) {
      int flat = (i * 256 + tid) * 8;
      int r = flat >> 6, c = flat & 63;
      __builtin_amdgcn_global_load_lds((const __attribute__((address_space(1))) void*)(Ag + (size_t)r * K + c),
                                       (__attribute__((address_space(3))) void*)(&As[r][c]), 16, 0, 0);
    }
    #pragma unroll
    for (int i = 0; i < 4; ++i) {
      int flat = (i * 256 + tid) * 8;
      int r = flat >> 6, c = flat & 63;
      __builtin_amdgcn_global_load_lds((const __attribute__((address_space(1))) void*)(Bg + (size_t)r * K + c),
                                       (__attribute__((address_space(3))) void*)(&Bs[r][c]), 16, 0, 0);
    }
    __syncthreads();

    #pragma unroll
    for (int ks = 0; ks < 2; ++ks) {
      bf16x8 af[4], bfr[4];
      #pragma unroll
      for (int i = 0; i < 4; ++i) af[i]  = ld_bf8(&As[wr + i * 16 + lrow][ks * 32 + lk8]);
      #pragma unroll
      for (int j = 0; j < 4; ++j) bfr[j] = ld_bf8(&Bs[wc + j * 16 + lrow][ks * 32 + lk8]);
      #pragma unroll
      for (int i = 0; i < 4; ++i)
        #pragma unroll
        for (int j = 0; j < 4; ++j)
          acc[i][j] = __builtin_amdgcn_mfma_f32_16x16x32_bf16(af[i], bfr[j], acc[i][j], 0, 0, 0);
    }
    __syncthreads();
  }

  const int rg = (lane >> 4) * 4;
  const int cl = lane & 15;
  #pragma unroll
  for (int i = 0; i < 4; ++i)
    #pragma unroll
    for (int j = 0; j < 4; ++j)
      #pragma unroll
      for (int rr = 0; rr < 4; ++rr) {
        int gm = row0 + wr + i * 16 + rg + rr;
        int gn = col0 + wc + j * 16 + cl;
        float v = acc[i][j][rr];
        if (OUT_BF16) ((unsigned short*)Cout)[(size_t)gm * N + gn] = f2bf(v);
        else          ((float*)Cout)[(size_t)gm * N + gn] = v;
      }
}

// ---------------- V transpose: qkv V-part -> vT[b][h][d][T] (unchanged, known-good) ----------------
__global__ __launch_bounds__(256) void vtrans_kernel(const unsigned short* __restrict__ qkv,
                                                     unsigned short* __restrict__ vT) {
  __shared__ __align__(16) unsigned short L[64 * 64];
  const int tid = threadIdx.x;
  const int t0  = blockIdx.x * 64;
  const int bh  = blockIdx.y;
  const int b   = bh >> 4;
  const int h   = bh & 15;
  const unsigned short* src = qkv + (size_t)b * Tn * (3 * Cn) + 2 * Cn + h * Dn;

  #pragma unroll
  for (int i = 0; i < 2; ++i) {
    int flat = i * 256 + tid;
    int t = flat >> 3, c = flat & 7;
    int cs = c ^ ((t >> 3) & 7);
    __builtin_amdgcn_global_load_lds(
        (const __attribute__((address_space(1))) void*)(src + (size_t)(t0 + t) * (3 * Cn) + cs * 8),
        (__attribute__((address_space(3))) void*)(&L[flat * 8]), 16, 0, 0);
  }
  __syncthreads();

  #pragma unroll
  for (int i = 0; i < 2; ++i) {
    int flat = i * 256 + tid;
    int d = flat >> 3, tc = flat & 7;
    u16x8 o;
    #pragma unroll
    for (int j = 0; j < 8; ++j) {
      int t = tc * 8 + j;
      o[j] = L[t * 64 + (((d >> 3) ^ ((t >> 3) & 7)) << 3) + (d & 7)];
    }
    *(u16x8*)(vT + ((size_t)bh * 64 + d) * Tn + t0 + tc * 8) = o;
  }
}

// ---------------- Causal flash attention ----------------
// Same structure as R4 (passed, 0 bank conflicts). Softmax changes:
//  - lrun is a PER-LANE PARTIAL sum (alpha row-uniform => exact); one 4-step
//    cross-lane reduce at the end. Deletes 16 shfl_xor per tile.
//  - exact skip-rescale: if pmax <= mrun for all rows in the wave (wave-uniform
//    branch), alpha == 1 exactly -> skip alpha exp + oacc rescale.
//  - P staging / output use HW bf16 cvt instead of hand-rolled f2bf.
__global__ __launch_bounds__(256) void attn_kernel(const unsigned short* __restrict__ qkv,
                                                   const unsigned short* __restrict__ vT,
                                                   unsigned short* __restrict__ outb) {
  __shared__ __align__(16) unsigned short Ks[2][4096];
  __shared__ __align__(16) unsigned short Vs[2][4096];
  __shared__ __align__(16) unsigned short Ps[4][1024];

  const int tid  = threadIdx.x;
  const int wave = tid >> 6;
  const int lane = tid & 63;
  const int cl   = lane & 15;
  const int g    = lane >> 4;
  const int lk8  = g << 3;
  const int rg   = g * 4;

  const int orig = blockIdx.y * gridDim.x + blockIdx.x;   // 0..2047
  const int cid  = (orig & 7) * 256 + (orig >> 3);
  const int qt   = (63 - (cid & 63)) * 64;
  const int bh   = cid >> 6;
  const int b    = bh >> 4;
  const int h    = bh & 15;

  const unsigned short* qb  = qkv + (size_t)b * Tn * (3 * Cn) + h * Dn;
  const unsigned short* kb  = qb + Cn;
  const unsigned short* vtb = vT + (size_t)bh * Dn * Tn;

  bf16x8 qf[2];
  {
    const unsigned short* qr = qb + (size_t)(qt + wave * 16 + cl) * (3 * Cn) + lk8;
    qf[0] = ld_bf8(qr);
    qf[1] = ld_bf8(qr + 32);
    #pragma unroll
    for (int j = 0; j < 8; ++j) {
      qf[0][j] = qf[0][j] * (__bf16)0.125f;   // exact exponent shift
      qf[1][j] = qf[1][j] * (__bf16)0.125f;
    }
  }

  f32x4 oacc[4];
  #pragma unroll
  for (int n = 0; n < 4; ++n) oacc[n] = (f32x4){0.f, 0.f, 0.f, 0.f};
  float mrun[4] = {-1e30f, -1e30f, -1e30f, -1e30f};
  float lrun[4] = {0.f, 0.f, 0.f, 0.f};   // per-lane partial denominators

  // ---- prologue: stage tile 0 into buffer 0 ----
  #pragma unroll
  for (int i = 0; i < 2; ++i) {
    const int flat = i * 256 + tid;
    const int r    = flat >> 3;
    const int cg   = flat & 7;
    const int sw   = cg ^ (r & 7);
    __builtin_amdgcn_global_load_lds(
        (const __attribute__((address_space(1))) void*)(kb + (size_t)r * (3 * Cn) + sw * 8),
        (__attribute__((address_space(3))) void*)(&Ks[0][flat * 8]), 16, 0, 0);
    __builtin_amdgcn_global_load_lds(
        (const __attribute__((address_space(1))) void*)(vtb + (size_t)r * Tn + sw * 8),
        (__attribute__((address_space(3))) void*)(&Vs[0][flat * 8]), 16, 0, 0);
  }
  __syncthreads();

  const int nkv = qt / 64 + 1;
  for (int kt = 0; kt < nkv; ++kt) {
    const int kv0 = kt * 64;
    const int cur = kt & 1;
    const int nb  = cur ^ 1;
    const bool pre = (kt + 1 < nkv);

    // ---- phase A: issue next tile's staging ----
    if (pre) {
      const int kv1 = kv0 + 64;
      #pragma unroll
      for (int i = 0; i < 2; ++i) {
        const int flat = i * 256 + tid;
        const int r    = flat >> 3;
        const int cg   = flat & 7;
        const int sw   = cg ^ (r & 7);
        __builtin_amdgcn_global_load_lds(
            (const __attribute__((address_space(1))) void*)(kb + (size_t)(kv1 + r) * (3 * Cn) + sw * 8),
            (__attribute__((address_space(3))) void*)(&Ks[nb][flat * 8]), 16, 0, 0);
        __builtin_amdgcn_global_load_lds(
            (const __attribute__((address_space(1))) void*)(vtb + (size_t)r * Tn + kv1 + sw * 8),
            (__attribute__((address_space(3))) void*)(&Vs[nb][flat * 8]), 16, 0, 0);
      }
    }

    // ---- phase B: compute tile kt ----
    f32x4 s[4];
    #pragma unroll
    for (int n = 0; n < 4; ++n) s[n] = (f32x4){0.f, 0.f, 0.f, 0.f};
    __builtin_amdgcn_s_setprio(1);
    #pragma unroll
    for (int n = 0; n < 4; ++n)
      #pragma unroll
      for (int ks = 0; ks < 2; ++ks) {
        bf16x8 kf = ld_bf8(&Ks[cur][(n * 16 + cl) * 64 + (((ks * 4 + g) ^ (cl & 7)) << 3)]);
        s[n] = __builtin_amdgcn_mfma_f32_16x16x32_bf16(qf[ks], kf, s[n], 0, 0, 0);
      }
    __builtin_amdgcn_s_setprio(0);

    // causal mask (scale already folded into Q)
    const bool diag = (kv0 == qt);
    if (diag) {
      #pragma unroll
      for (int n = 0; n < 4; ++n)
        #pragma unroll
        for (int rr = 0; rr < 4; ++rr) {
          int ql = wave * 16 + rg + rr;
          int kl = n * 16 + cl;
          if (kl > ql) s[n][rr] = -1e30f;
        }
    }

    // ---- online softmax: tile max per row ----
    float pmax[4];
    #pragma unroll
    for (int rr = 0; rr < 4; ++rr) {
      float mx = fmaxf(fmaxf(s[0][rr], s[1][rr]), fmaxf(s[2][rr], s[3][rr]));
      mx = fmaxf(mx, __shfl_xor(mx, 1));
      mx = fmaxf(mx, __shfl_xor(mx, 2));
      mx = fmaxf(mx, __shfl_xor(mx, 4));
      mx = fmaxf(mx, __shfl_xor(mx, 8));
      pmax[rr] = mx;
    }
    const bool need = (pmax[0] > mrun[0]) || (pmax[1] > mrun[1]) ||
                      (pmax[2] > mrun[2]) || (pmax[3] > mrun[3]);
    if (__any(need)) {
      #pragma unroll
      for (int rr = 0; rr < 4; ++rr) {
        float mnew  = fmaxf(mrun[rr], pmax[rr]);
        float alpha = __expf(mrun[rr] - mnew);
        mrun[rr] = mnew;
        float psum = 0.f;
        #pragma unroll
        for (int n = 0; n < 4; ++n) {
          float p = __expf(s[n][rr] - mnew);
          s[n][rr] = p;
          psum += p;
        }
        lrun[rr] = lrun[rr] * alpha + psum;
        #pragma unroll
        for (int n = 0; n < 4; ++n) oacc[n][rr] *= alpha;
      }
    } else {   // pmax <= mrun for every row in wave: alpha == 1 exactly
      #pragma unroll
      for (int rr = 0; rr < 4; ++rr) {
        float psum = 0.f;
        #pragma unroll
        for (int n = 0; n < 4; ++n) {
          float p = __expf(s[n][rr] - mrun[rr]);
          s[n][rr] = p;
          psum += p;
        }
        lrun[rr] += psum;
      }
    }

    // stage P (wave-private, slot XOR-swizzled by row&7)
    #pragma unroll
    for (int n = 0; n < 4; ++n)
      #pragma unroll
      for (int rr = 0; rr < 4; ++rr) {
        const int row  = rg + rr;
        const int slot = n * 2 + (cl >> 3);
        Ps[wave][row * 64 + ((slot ^ (row & 7)) << 3) + (cl & 7)] = f2bf_hw(s[n][rr]);
      }

    // O += P @ V
    #pragma unroll
    for (int ks = 0; ks < 2; ++ks) {
      bf16x8 pa = ld_bf8(&Ps[wave][cl * 64 + (((ks * 4 + g) ^ (cl & 7)) << 3)]);
      __builtin_amdgcn_s_setprio(1);
      #pragma unroll
      for (int n = 0; n < 4; ++n) {
        bf16x8 vf = ld_bf8(&Vs[cur][(n * 16 + cl) * 64 + (((ks * 4 + g) ^ (cl & 7)) << 3)]);
        oacc[n] = __builtin_amdgcn_mfma_f32_16x16x32_bf16(pa, vf, oacc[n], 0, 0, 0);
      }
      __builtin_amdgcn_s_setprio(0);
    }

    __syncthreads();
  }

  // ---- final cross-lane denominator reduce (once), normalize, write ----
  #pragma unroll
  for (int rr = 0; rr < 4; ++rr) {
    lrun[rr] += __shfl_xor(lrun[rr], 1);
    lrun[rr] += __shfl_xor(lrun[rr], 2);
    lrun[rr] += __shfl_xor(lrun[rr], 4);
    lrun[rr] += __shfl_xor(lrun[rr], 8);
  }
  #pragma unroll
  for (int rr = 0; rr < 4; ++rr) {
    float inv = 1.0f / lrun[rr];
    int t = qt + wave * 16 + rg + rr;
    size_t rowo = ((size_t)b * Tn + t) * Cn + h * Dn;
    #pragma unroll
    for (int n = 0; n < 4; ++n)
      outb[rowo + n * 16 + cl] = f2bf_hw(oacc[n][rr] * inv);
  }
}

extern "C" void kernel_launch(void* const* d_in, const int* in_sizes, int n_in,
                              void* d_out, int out_size, void* d_ws, size_t ws_size,
                              hipStream_t stream) {
  const float* x    = (const float*)d_in[0];
  const float* Wqkv = (const float*)d_in[1];
  const float* Wout = (const float*)d_in[2];
  float* y = (float*)d_out;

  unsigned short* xb    = (unsigned short*)d_ws;               // reused as vT after gemm1
  unsigned short* wqkvb = xb    + (size_t)Bn * Tn * Cn;
  unsigned short* woutb = wqkvb + (size_t)3 * Cn * Cn;
  unsigned short* qkvb  = woutb + (size_t)Cn * Cn;
  unsigned short* attno = qkvb  + (size_t)Bn * Tn * 3 * Cn;

  const int M = Bn * Tn;  // 8192

  {
    int n4 = (Bn * Tn * Cn) / 4;
    cvt_kernel<<<(n4 + 255) / 256, 256, 0, stream>>>(x, xb, n4);
  }
  {
    int n4 = (3 * Cn * Cn) / 4;
    cvt_kernel<<<(n4 + 255) / 256, 256, 0, stream>>>(Wqkv, wqkvb, n4);
  }
  {
    int n4 = (Cn * Cn) / 4;
    cvt_kernel<<<(n4 + 255) / 256, 256, 0, stream>>>(Wout, woutb, n4);
  }

  gemm_bt<1><<<dim3(3 * Cn / 128, M / 128), 256, 0, stream>>>(xb, wqkvb, qkvb, M, 3 * Cn, Cn);

  unsigned short* vT = xb;
  vtrans_kernel<<<dim3(Tn / 64, Bn * Hn), 256, 0, stream>>>(qkvb, vT);

  attn_kernel<<<dim3(Tn / 64, Bn * Hn), 256, 0, stream>>>(qkvb, vT, attno);

  gemm_bt<0><<<dim3(Cn / 128, M / 128), 256, 0, stream>>>(attno, woutb, y, M, Cn, Cn);

  (void)in_sizes; (void)n_in; (void)out_size; (void)ws_size;
}